// Round 1
// baseline (175.253 us; speedup 1.0000x reference)
//
#include <hip/hip_runtime.h>
#include <cfloat>
#include <cmath>

#define NPTS 131072
#define NC   512
#define NREP 4
#define L2E  1.4426950408889634f
#define LN2  0.6931471805599453f
// log2-domain relevance cutoff: gamma < 2^-34 contributes < 6e-11 per pair.
#define CUT  34.0f

// ws float-index layout (unchanged):
//  PM4  [0, 2048)      : per-component float4, BASE-2 scaled (2*mu*k2, w*log2e - |mu|^2*k2)
//  PQ4  [2048, 4096)   : per-component float4 (mu_new[3], A_c)
//  ST4  [4096, 12288)  : NREP replicas x 512 comps x float4 (Tx,Ty,Tz,S)
//  MISC [12288, 12296) : [0]=sum|x|^2, [1]=inv2s2_new, [3]=sum(gamma*lgamma)
// z_n (base-2 units) staged in d_out[3n] (k_estep writes, k_final reads then overwrites).
#define PM4_OFF  0
#define PQ4_OFF  2048
#define ST4_OFF  4096
#define MISC_OFF 12288

__device__ __forceinline__ float waveSum(float v) {
#pragma unroll
  for (int off = 32; off > 0; off >>= 1) v += __shfl_down(v, off, 64);
  return v;
}
__device__ __forceinline__ float waveMax(float v) {
#pragma unroll
  for (int off = 32; off > 0; off >>= 1) v = fmaxf(v, __shfl_down(v, off, 64));
  return v;
}

// ---------------------------------------------------------------------------
// Prep: fold sigma/mu/w into packed pm, pre-scaled by log2(e) so every exp is
// a single v_exp_f32 (base-2). Zero ST replicas + misc.
// ---------------------------------------------------------------------------
__global__ __launch_bounds__(512) void k_prep(
    const float* __restrict__ mu, const float* __restrict__ w,
    const float* __restrict__ sigma, float4* __restrict__ pm,
    float* __restrict__ ST, float* __restrict__ misc) {
  const int t = threadIdx.x;  // component id
  const float sg = sigma[0];
  const float k2 = L2E / (2.0f * sg * sg);  // log2e * inv2s2
  const float m0 = mu[3 * t], m1 = mu[3 * t + 1], m2 = mu[3 * t + 2];
  pm[t] = make_float4(2.0f * k2 * m0, 2.0f * k2 * m1, 2.0f * k2 * m2,
                      w[t] * L2E - (m0 * m0 + m1 * m1 + m2 * m2) * k2);
#pragma unroll
  for (int r = 0; r < NREP * 4; ++r) ST[r * 512 + t] = 0.f;
  if (t < 8) misc[t] = 0.f;
}

// ---------------------------------------------------------------------------
// E-step: block = 512 thr = 64 points x 8 comp-chunks (64 comps each).
// Pass 1 (dense, irreducible): l[i] kept in VGPRs + per-thread max.
// Pass 2 (gated): sumexp + q = sum e*(l-M) only where l >= M-CUT.
//   La per point = ln2*(q/s - log2 s)  (identity: sum g*(l-z), sum g = 1).
// Pass 3 (gated): point-side accumulation of (g*x, g) into per-comp LDS
//   accumulators via LDS atomics (lanes = 64 distinct points, comp is
//   wave-uniform per unrolled i -> whole-wave exec-mask skip when no hits).
// Flush: one global ST atomic per *touched* comp per block.
// ---------------------------------------------------------------------------
__global__ __launch_bounds__(512, 4) void k_estep(
    const float* __restrict__ X, const float4* __restrict__ pm,
    float* __restrict__ ST, float* __restrict__ misc,
    float* __restrict__ out) {
  __shared__ float  s_m[8][64];   // per-(chunk,point) max
  __shared__ float2 s_sq[8][64];  // per-(chunk,point) (sumexp, q)
  __shared__ float  s_M[64];      // per-point global max
  __shared__ float  s_z[64];      // per-point z (base-2)
  __shared__ float4 s_acc[NC];    // per-comp (Tx,Ty,Tz,S)

  const int t = threadIdx.x;
  const int p = t & 63;
  const int ch = __builtin_amdgcn_readfirstlane(t >> 6);  // wave-uniform
  const int n = blockIdx.x * 64 + p;
  const float x0 = X[3 * n], x1 = X[3 * n + 1], x2 = X[3 * n + 2];

  s_acc[t] = make_float4(0.f, 0.f, 0.f, 0.f);

  // --- pass 1: dense l + max; l[] stays in VGPRs (static indexing only) ---
  const float4* __restrict__ pmc = pm + ch * 64;  // wave-uniform pointer
  float l[64];
  float ma = -FLT_MAX, mb = -FLT_MAX, mc2 = -FLT_MAX, md = -FLT_MAX;
#pragma unroll
  for (int i = 0; i < 64; i += 4) {
    float4 a = pmc[i], b = pmc[i + 1], c = pmc[i + 2], d = pmc[i + 3];
    l[i]     = fmaf(a.x, x0, fmaf(a.y, x1, fmaf(a.z, x2, a.w)));
    l[i + 1] = fmaf(b.x, x0, fmaf(b.y, x1, fmaf(b.z, x2, b.w)));
    l[i + 2] = fmaf(c.x, x0, fmaf(c.y, x1, fmaf(c.z, x2, c.w)));
    l[i + 3] = fmaf(d.x, x0, fmaf(d.y, x1, fmaf(d.z, x2, d.w)));
    ma  = fmaxf(ma, l[i]);      mb = fmaxf(mb, l[i + 1]);
    mc2 = fmaxf(mc2, l[i + 2]); md = fmaxf(md, l[i + 3]);
  }
  s_m[ch][p] = fmaxf(fmaxf(ma, mb), fmaxf(mc2, md));
  __syncthreads();

  if (t < 64) {  // p == t here
    float v = s_m[0][t];
#pragma unroll
    for (int c = 1; c < 8; ++c) v = fmaxf(v, s_m[c][t]);
    s_M[t] = v;
  }
  __syncthreads();

  const float M = s_M[p];
  const float thr = M - CUT;

  // --- pass 2: gated sumexp + q over register-resident l ---
  float sE = 0.f, qE = 0.f;
#pragma unroll
  for (int i = 0; i < 64; ++i) {
    if (l[i] >= thr) {
      const float d = l[i] - M;
      const float e = exp2f(d);
      sE += e;
      qE = fmaf(e, d, qE);
    }
  }
  s_sq[ch][p] = make_float2(sE, qE);
  __syncthreads();

  if (t < 64) {  // p == t; combine 8 chunks, emit z, La, |x|^2
    float ss = 0.f, qq = 0.f;
#pragma unroll
    for (int c = 0; c < 8; ++c) { float2 v = s_sq[c][t]; ss += v.x; qq += v.y; }
    const float lg = __log2f(ss);           // ss >= 1 always (max term included)
    const float z = s_M[t] + lg;
    s_z[t] = z;
    out[3 * n] = z;                         // staged for k_final (base-2)
    const float La = LN2 * (__fdividef(qq, ss) - lg);  // sum_c gamma*lgamma
    const float xx = x0 * x0 + x1 * x1 + x2 * x2;
    const float rl = waveSum(La);
    const float rx = waveSum(xx);
    if (t == 0) { atomicAdd(&misc[3], rl); atomicAdd(&misc[0], rx); }
  }
  __syncthreads();

  // --- pass 3: gated accumulation, point-side -> per-comp LDS atomics ---
  const float z = s_z[p];
#pragma unroll
  for (int i = 0; i < 64; ++i) {
    if (l[i] >= thr) {
      const float g = exp2f(l[i] - z);
      float* a = (float*)(s_acc + (ch * 64 + i));  // wave-uniform address
      atomicAdd(a + 0, g * x0);
      atomicAdd(a + 1, g * x1);
      atomicAdd(a + 2, g * x2);
      atomicAdd(a + 3, g);
    }
  }
  __syncthreads();

  // --- flush touched comps to the ST replica for this block ---
  float4 v = s_acc[t];
  if (v.w != 0.f) {  // g > 0 strictly on any hit (exponent >= -34, no underflow)
    float* st = ST + (((blockIdx.x & (NREP - 1)) * 512 + t) << 2);
    atomicAdd(st + 0, v.x);
    atomicAdd(st + 1, v.y);
    atomicAdd(st + 2, v.z);
    atomicAdd(st + 3, v.w);
  }
}

// ---------------------------------------------------------------------------
// M-step: one block, 512 threads (one per component). Unchanged math
// (natural-log domain; only pm is base-2 scaled, and mstep doesn't read pm).
// ---------------------------------------------------------------------------
__global__ __launch_bounds__(512) void k_mstep(
    const float* __restrict__ mu, const float4* __restrict__ ST4,
    float4* __restrict__ pq, float* __restrict__ misc,
    float* __restrict__ out) {
  __shared__ float s_red[8];
  __shared__ float s_red2[8];
  __shared__ float s_bc[4];
  const int t = threadIdx.x;

  float Tx = 0.f, Ty = 0.f, Tz = 0.f, S = 0.f;
#pragma unroll
  for (int r = 0; r < NREP; ++r) {
    float4 v = ST4[r * 512 + t];
    Tx += v.x; Ty += v.y; Tz += v.z; S += v.w;
  }
  const float Sc = fmaxf(S, 1e-30f);
  const float h = __logf(Sc);
  const float m0 = Tx / Sc, m1 = Ty / Sc, m2 = Tz / Sc;

  const float o0 = mu[3 * t], o1 = mu[3 * t + 1], o2 = mu[3 * t + 2];
  const float gdp = S * (o0 * o0 + o1 * o1 + o2 * o2)
                    - 2.0f * (o0 * Tx + o1 * Ty + o2 * Tz);

  float hm = waveMax(h);
  if ((t & 63) == 0) s_red[t >> 6] = hm;
  __syncthreads();
  if (t == 0) {
    float v = s_red[0];
    for (int i = 1; i < 8; ++i) v = fmaxf(v, s_red[i]);
    s_bc[0] = v;
  }
  __syncthreads();
  const float hM = s_bc[0];

  float es = waveSum(__expf(h - hM));
  float gs = waveSum(gdp);
  if ((t & 63) == 0) { s_red[t >> 6] = es; s_red2[t >> 6] = gs; }
  __syncthreads();
  if (t == 0) {
    float esum = 0.f, gsum = 0.f;
    for (int i = 0; i < 8; ++i) { esum += s_red[i]; gsum += s_red2[i]; }
    s_bc[1] = hM + __logf(esum);                           // lse(h)
    const float gd = fmaxf(misc[0] + gsum, 1e-20f);
    const float sn2 = gd * (1.0f / (3.0f * (float)NPTS));  // sigma_new^2
    s_bc[2] = 1.0f / (2.0f * sn2);                         // inv2s2_new
    s_bc[3] = 1.5f * __logf(sn2);                          // d*log(sigma_new)
  }
  __syncthreads();

  const float inv2s2n = s_bc[2];
  const float logpi = h - s_bc[1];
  const float A = (m0 * m0 + m1 * m1 + m2 * m2) * inv2s2n - logpi;
  pq[t] = make_float4(m0, m1, m2, A);

  float ca = waveSum(S * A);
  if ((t & 63) == 0) s_red[t >> 6] = ca;
  __syncthreads();
  if (t == 0) {
    float v = 0.f;
    for (int i = 0; i < 8; ++i) v += s_red[i];
    out[NPTS * 3] = v + misc[3] + (float)NPTS * s_bc[3];
    misc[1] = inv2s2n;
  }
}

// ---------------------------------------------------------------------------
// Final: block = 512 thr = 128 points x 4 chunks. Dense l scan (3 FMA + cmp),
// exp + Y-FMA only where l >= z - CUT (~2-3 comps/point). pm/pq LDS-staged.
// Cfe contribution is -|Y|^2 * inv2s2n per point (rest seeded in k_mstep).
// ---------------------------------------------------------------------------
__global__ __launch_bounds__(512, 4) void k_final(
    const float* __restrict__ X, const float4* __restrict__ pm,
    const float4* __restrict__ pq, const float* __restrict__ misc,
    float* __restrict__ out) {
  __shared__ float4 s_pm[NC];
  __shared__ float4 s_pq[NC];
  __shared__ float4 s_y[4][128];
  __shared__ float  s_red[8];

  const int t = threadIdx.x;
  const int p = t & 127;
  const int ch = __builtin_amdgcn_readfirstlane(t >> 7);
  const int n = blockIdx.x * 128 + p;

  s_pm[t] = pm[t];
  s_pq[t] = pq[t];

  const float x0 = X[3 * n], x1 = X[3 * n + 1], x2 = X[3 * n + 2];
  const float z = out[3 * n];  // staged by k_estep; overwritten after barrier
  const float thr = z - CUT;
  const float inv2s2n = misc[1];
  __syncthreads();

  const float4* __restrict__ pmc = &s_pm[ch * 128];
  const float4* __restrict__ pqc = &s_pq[ch * 128];
  float y0 = 0.f, y1 = 0.f, y2 = 0.f;
#pragma unroll 8
  for (int i = 0; i < 128; ++i) {
    float4 pp = pmc[i];  // LDS broadcast (wave-uniform i)
    const float l = fmaf(pp.x, x0, fmaf(pp.y, x1, fmaf(pp.z, x2, pp.w)));
    if (l >= thr) {
      const float g = exp2f(l - z);
      float4 qq = pqc[i];
      y0 = fmaf(g, qq.x, y0);
      y1 = fmaf(g, qq.y, y1);
      y2 = fmaf(g, qq.z, y2);
    }
  }
  s_y[ch][p] = make_float4(y0, y1, y2, 0.f);
  __syncthreads();

  float cfe = 0.f;
  if (t < 128) {  // p == t here
    float4 a0 = s_y[0][t], a1 = s_y[1][t], a2 = s_y[2][t], a3 = s_y[3][t];
    const float Y0 = (a0.x + a1.x) + (a2.x + a3.x);
    const float Y1 = (a0.y + a1.y) + (a2.y + a3.y);
    const float Y2 = (a0.z + a1.z) + (a2.z + a3.z);
    cfe = -(Y0 * Y0 + Y1 * Y1 + Y2 * Y2) * inv2s2n;
    out[3 * n] = Y0;
    out[3 * n + 1] = Y1;
    out[3 * n + 2] = Y2;
  }
  float r = waveSum(cfe);
  if ((t & 63) == 0) s_red[t >> 6] = r;
  __syncthreads();
  if (t == 0) {
    float v = 0.f;
#pragma unroll
    for (int i = 0; i < 8; ++i) v += s_red[i];
    atomicAdd(&out[NPTS * 3], v);
  }
}

extern "C" void kernel_launch(void* const* d_in, const int* in_sizes, int n_in,
                              void* d_out, int out_size, void* d_ws, size_t ws_size,
                              hipStream_t stream) {
  const float* X = (const float*)d_in[0];
  const float* mu = (const float*)d_in[1];
  const float* w = (const float*)d_in[2];
  const float* sigma = (const float*)d_in[3];
  float* out = (float*)d_out;
  float* ws = (float*)d_ws;

  float4* pm = (float4*)(ws + PM4_OFF);
  float4* pq = (float4*)(ws + PQ4_OFF);
  float* ST = ws + ST4_OFF;
  float* misc = ws + MISC_OFF;

  k_prep<<<1, 512, 0, stream>>>(mu, w, sigma, pm, ST, misc);
  k_estep<<<NPTS / 64, 512, 0, stream>>>(X, pm, ST, misc, out);
  k_mstep<<<1, 512, 0, stream>>>(mu, (const float4*)ST, pq, misc, out);
  k_final<<<NPTS / 128, 512, 0, stream>>>(X, pm, pq, misc, out);
}

// Round 2
// 161.255 us; speedup vs baseline: 1.0868x; 1.0868x over previous
//
#include <hip/hip_runtime.h>
#include <cfloat>
#include <cmath>

#define NPTS 131072
#define NC   512
#define NREP 4
#define L2E  1.4426950408889634f
#define LN2  0.6931471805599453f
// log2-domain relevance cutoff: gamma < 2^-34 contributes < 6e-11 per pair.
// Validated: rounds 0/1 have identical absmax with/without this cut.
#define CUT  34.0f
#define ECAP 2048   // block-level entry capacity (mean ~350, Poisson: never hit)
#define PK   15     // per-point id slots (P(count>15) ~ 1e-9 per point)

// ws float-index layout:
//  PM4  [0, 2048)      : per-component float4, BASE-2 scaled (2*mu*k2, w*log2e - |mu|^2*k2)
//  PQ4  [2048, 4096)   : per-component float4 (mu_new[3], A_c)
//  ST4  [4096, 12288)  : NREP replicas x 512 comps x float4 (Tx,Ty,Tz,S)
//  MISC [12288, 12296) : [0]=sum|x|^2, [1]=inv2s2_new, [3]=sum(gamma*lgamma)
//  PL   [16384, ...)   : per-point u16[16]: [cnt|0xFFFF, id0..id14]  (4 MB)
// z_n (base-2 units) staged in d_out[3n] (k_estep writes, k_final reads then overwrites).
#define PM4_OFF  0
#define PQ4_OFF  2048
#define ST4_OFF  4096
#define MISC_OFF 12288
#define PL_OFF   16384

__device__ __forceinline__ float waveSum(float v) {
#pragma unroll
  for (int off = 32; off > 0; off >>= 1) v += __shfl_down(v, off, 64);
  return v;
}
__device__ __forceinline__ float waveMax(float v) {
#pragma unroll
  for (int off = 32; off > 0; off >>= 1) v = fmaxf(v, __shfl_down(v, off, 64));
  return v;
}

// ---------------------------------------------------------------------------
// Prep: fold sigma/mu/w into packed pm, base-2 scaled (each exp = v_exp_f32).
// ---------------------------------------------------------------------------
__global__ __launch_bounds__(512) void k_prep(
    const float* __restrict__ mu, const float* __restrict__ w,
    const float* __restrict__ sigma, float4* __restrict__ pm,
    float* __restrict__ ST, float* __restrict__ misc) {
  const int t = threadIdx.x;  // component id
  const float sg = sigma[0];
  const float k2 = L2E / (2.0f * sg * sg);  // log2e * inv2s2
  const float m0 = mu[3 * t], m1 = mu[3 * t + 1], m2 = mu[3 * t + 2];
  pm[t] = make_float4(2.0f * k2 * m0, 2.0f * k2 * m1, 2.0f * k2 * m2,
                      w[t] * L2E - (m0 * m0 + m1 * m1 + m2 * m2) * k2);
#pragma unroll
  for (int r = 0; r < NREP * 4; ++r) ST[r * 512 + t] = 0.f;
  if (t < 8) misc[t] = 0.f;
}

// ---------------------------------------------------------------------------
// E-step: block = 512 thr = 128 points x 4 comp-chunks (128 comps each).
// Pass 1 (dense): l + per-chunk max; NO per-thread array (round-0 codegen).
// Combine -> per-point global max M.
// Pass 2 (dense recompute + gated tail): l; if l >= M-CUT: (sE,qE) accum,
//   push (p,c,l) to block entry list, push c to per-point global u16 list.
// Combine -> z, La (identity), cnt writeback, misc reductions.
// Pass 3: iterate ~350 entries; g = 2^(l-z); 4 global ST atomics each.
// ---------------------------------------------------------------------------
__global__ __launch_bounds__(512, 4) void k_estep(
    const float* __restrict__ X, const float4* __restrict__ pm,
    float* __restrict__ ST, float* __restrict__ misc,
    float* __restrict__ out, unsigned short* __restrict__ plist) {
  __shared__ float4 s_pt[128];      // x0,x1,x2, (.w = z after combine2)
  __shared__ float  s_m[4][128];    // per-(chunk,point) max
  __shared__ float2 s_sq[4][128];   // per-(chunk,point) (sumexp, q)
  __shared__ float  s_M[128];       // per-point global max
  __shared__ unsigned int s_cnt;    // block entry count
  __shared__ unsigned int s_pcnt[128];
  __shared__ unsigned int s_ec[ECAP];  // packed (p<<16)|c
  __shared__ float        s_el[ECAP];  // l for that entry

  const int t = threadIdx.x;
  const int p = t & 127;
  const int ch = __builtin_amdgcn_readfirstlane(t >> 7);  // wave-uniform
  const int n = blockIdx.x * 128 + p;
  const float x0 = X[3 * n], x1 = X[3 * n + 1], x2 = X[3 * n + 2];

  if (t == 0) s_cnt = 0u;
  if (t < 128) {
    s_pcnt[t] = 0u;
    s_pt[t] = make_float4(x0, x1, x2, 0.f);  // p == t here
  }

  // --- pass 1: dense l + chunk max (no storage) ---
  const float4* __restrict__ pmc = pm + ch * 128;  // wave-uniform
  float ma = -FLT_MAX, mb = -FLT_MAX, mc2 = -FLT_MAX, md = -FLT_MAX;
#pragma unroll 4
  for (int i = 0; i < 128; i += 4) {
    float4 a = pmc[i], b = pmc[i + 1], c = pmc[i + 2], d = pmc[i + 3];
    ma  = fmaxf(ma,  fmaf(a.x, x0, fmaf(a.y, x1, fmaf(a.z, x2, a.w))));
    mb  = fmaxf(mb,  fmaf(b.x, x0, fmaf(b.y, x1, fmaf(b.z, x2, b.w))));
    mc2 = fmaxf(mc2, fmaf(c.x, x0, fmaf(c.y, x1, fmaf(c.z, x2, c.w))));
    md  = fmaxf(md,  fmaf(d.x, x0, fmaf(d.y, x1, fmaf(d.z, x2, d.w))));
  }
  s_m[ch][p] = fmaxf(fmaxf(ma, mb), fmaxf(mc2, md));
  __syncthreads();  // B1 (also publishes init writes)

  if (t < 128) {
    float v = fmaxf(fmaxf(s_m[0][t], s_m[1][t]), fmaxf(s_m[2][t], s_m[3][t]));
    s_M[t] = v;
  }
  __syncthreads();  // B2

  const float M = s_M[p];
  const float thr = M - CUT;

  // --- pass 2: dense recompute, gated accumulate + list push ---
  float sE = 0.f, qE = 0.f;
#pragma unroll 4
  for (int i = 0; i < 128; ++i) {
    float4 a = pmc[i];
    const float l = fmaf(a.x, x0, fmaf(a.y, x1, fmaf(a.z, x2, a.w)));
    if (l >= thr) {                      // whole-wave skip ~73% of iters
      const float d = l - M;
      const float e = exp2f(d);
      sE += e;
      qE = fmaf(e, d, qE);
      unsigned int idx = atomicAdd(&s_cnt, 1u);
      if (idx < (unsigned)ECAP) {
        s_ec[idx] = ((unsigned)p << 16) | (unsigned)(ch * 128 + i);
        s_el[idx] = l;
      }
      if (plist) {
        unsigned int slot = atomicAdd(&s_pcnt[p], 1u);
        if (slot < (unsigned)PK)
          plist[(size_t)n * 16u + 1u + slot] = (unsigned short)(ch * 128 + i);
      } else {
        atomicAdd(&s_pcnt[p], 1u);
      }
    }
  }
  s_sq[ch][p] = make_float2(sE, qE);
  __syncthreads();  // B3

  if (t < 128) {  // p == t: combine chunks; emit z, La, cnt, reductions
    float2 q0 = s_sq[0][t], q1 = s_sq[1][t], q2 = s_sq[2][t], q3 = s_sq[3][t];
    const float ss = (q0.x + q1.x) + (q2.x + q3.x);  // >= 1 (max term present)
    const float qq = (q0.y + q1.y) + (q2.y + q3.y);
    const float lg = __log2f(ss);
    const float z = s_M[t] + lg;
    s_pt[t].w = z;
    out[3 * n] = z;  // staged for k_final (base-2)
    if (plist) {
      unsigned int pc = s_pcnt[t];
      plist[(size_t)n * 16u] =
          (pc > (unsigned)PK) ? (unsigned short)0xFFFFu : (unsigned short)pc;
    }
    const float La = LN2 * (__fdividef(qq, ss) - lg);  // sum_c gamma*lgamma
    const float xx = x0 * x0 + x1 * x1 + x2 * x2;
    const float rl = waveSum(La);
    const float rx = waveSum(xx);
    if ((t & 63) == 0) { atomicAdd(&misc[3], rl); atomicAdd(&misc[0], rx); }
  }
  __syncthreads();  // B4

  // --- pass 3: entries -> global ST atomics (replica blockIdx&3) ---
  const unsigned int total = min(s_cnt, (unsigned)ECAP);
  float* __restrict__ stbase = ST + ((blockIdx.x & (NREP - 1)) * 512) * 4;
  for (unsigned int idx = t; idx < total; idx += 512) {
    const unsigned int ec = s_ec[idx];
    const unsigned int pp = ec >> 16;
    const unsigned int c = ec & 0xFFFFu;
    const float4 pt = s_pt[pp];
    const float g = exp2f(s_el[idx] - pt.w);
    float* st = stbase + c * 4;
    atomicAdd(st + 0, g * pt.x);
    atomicAdd(st + 1, g * pt.y);
    atomicAdd(st + 2, g * pt.z);
    atomicAdd(st + 3, g);
  }
}

// ---------------------------------------------------------------------------
// M-step: one block, 512 threads (one per component). Unchanged math.
// ---------------------------------------------------------------------------
__global__ __launch_bounds__(512) void k_mstep(
    const float* __restrict__ mu, const float4* __restrict__ ST4,
    float4* __restrict__ pq, float* __restrict__ misc,
    float* __restrict__ out) {
  __shared__ float s_red[8];
  __shared__ float s_red2[8];
  __shared__ float s_bc[4];
  const int t = threadIdx.x;

  float Tx = 0.f, Ty = 0.f, Tz = 0.f, S = 0.f;
#pragma unroll
  for (int r = 0; r < NREP; ++r) {
    float4 v = ST4[r * 512 + t];
    Tx += v.x; Ty += v.y; Tz += v.z; S += v.w;
  }
  const float Sc = fmaxf(S, 1e-30f);
  const float h = __logf(Sc);
  const float m0 = Tx / Sc, m1 = Ty / Sc, m2 = Tz / Sc;

  const float o0 = mu[3 * t], o1 = mu[3 * t + 1], o2 = mu[3 * t + 2];
  const float gdp = S * (o0 * o0 + o1 * o1 + o2 * o2)
                    - 2.0f * (o0 * Tx + o1 * Ty + o2 * Tz);

  float hm = waveMax(h);
  if ((t & 63) == 0) s_red[t >> 6] = hm;
  __syncthreads();
  if (t == 0) {
    float v = s_red[0];
    for (int i = 1; i < 8; ++i) v = fmaxf(v, s_red[i]);
    s_bc[0] = v;
  }
  __syncthreads();
  const float hM = s_bc[0];

  float es = waveSum(__expf(h - hM));
  float gs = waveSum(gdp);
  if ((t & 63) == 0) { s_red[t >> 6] = es; s_red2[t >> 6] = gs; }
  __syncthreads();
  if (t == 0) {
    float esum = 0.f, gsum = 0.f;
    for (int i = 0; i < 8; ++i) { esum += s_red[i]; gsum += s_red2[i]; }
    s_bc[1] = hM + __logf(esum);                           // lse(h)
    const float gd = fmaxf(misc[0] + gsum, 1e-20f);
    const float sn2 = gd * (1.0f / (3.0f * (float)NPTS));  // sigma_new^2
    s_bc[2] = 1.0f / (2.0f * sn2);                         // inv2s2_new
    s_bc[3] = 1.5f * __logf(sn2);                          // d*log(sigma_new)
  }
  __syncthreads();

  const float inv2s2n = s_bc[2];
  const float logpi = h - s_bc[1];
  const float A = (m0 * m0 + m1 * m1 + m2 * m2) * inv2s2n - logpi;
  pq[t] = make_float4(m0, m1, m2, A);

  float ca = waveSum(S * A);
  if ((t & 63) == 0) s_red[t >> 6] = ca;
  __syncthreads();
  if (t == 0) {
    float v = 0.f;
    for (int i = 0; i < 8; ++i) v += s_red[i];
    out[NPTS * 3] = v + misc[3] + (float)NPTS * s_bc[3];
    misc[1] = inv2s2n;
  }
}

// ---------------------------------------------------------------------------
// Final (list): thread-per-point, 512/block, grid NPTS/512. Reads the
// per-point id list (avg ~2.5 comps); pm/pq LDS-staged for scattered reads.
// Sentinel cnt=0xFFFF -> per-lane dense fallback (rare to nonexistent).
// ---------------------------------------------------------------------------
__global__ __launch_bounds__(512, 4) void k_final_list(
    const float* __restrict__ X, const float4* __restrict__ pm,
    const float4* __restrict__ pq, const float* __restrict__ misc,
    float* __restrict__ out, const unsigned short* __restrict__ plist) {
  __shared__ float4 s_pm[NC];
  __shared__ float4 s_pq[NC];
  __shared__ float  s_red[8];

  const int t = threadIdx.x;
  const int n = blockIdx.x * 512 + t;

  s_pm[t] = pm[t];
  s_pq[t] = pq[t];

  const float x0 = X[3 * n], x1 = X[3 * n + 1], x2 = X[3 * n + 2];
  const float z = out[3 * n];  // staged by k_estep (base-2)
  const float inv2s2n = misc[1];

  const uint4* __restrict__ lp =
      reinterpret_cast<const uint4*>(plist) + ((size_t)n << 1);
  const uint4 wA = lp[0];
  const uint4 wB = lp[1];
  unsigned int words[8] = {wA.x, wA.y, wA.z, wA.w, wB.x, wB.y, wB.z, wB.w};
  const unsigned int cnt = words[0] & 0xFFFFu;
  __syncthreads();

  float y0 = 0.f, y1 = 0.f, y2 = 0.f;
  if (cnt == 0xFFFFu) {
    // dense fallback for overflowed points (astronomically rare)
    const float thr = z - CUT;
    for (int c = 0; c < NC; ++c) {
      float4 pp = s_pm[c];
      const float l = fmaf(pp.x, x0, fmaf(pp.y, x1, fmaf(pp.z, x2, pp.w)));
      if (l >= thr) {
        const float g = exp2f(l - z);
        float4 qq = s_pq[c];
        y0 = fmaf(g, qq.x, y0);
        y1 = fmaf(g, qq.y, y1);
        y2 = fmaf(g, qq.z, y2);
      }
    }
  } else {
    const int ic = (int)cnt;
#pragma unroll
    for (int j = 0; j < PK; ++j) {
      if (!__any(j < ic)) break;  // wave-uniform early exit (max cnt ~6)
      if (j < ic) {
        const unsigned int word = words[(j + 1) >> 1];
        const unsigned int c =
            ((j + 1) & 1) ? (word >> 16) : (word & 0xFFFFu);
        float4 pp = s_pm[c];
        const float l = fmaf(pp.x, x0, fmaf(pp.y, x1, fmaf(pp.z, x2, pp.w)));
        const float g = exp2f(l - z);
        float4 qq = s_pq[c];
        y0 = fmaf(g, qq.x, y0);
        y1 = fmaf(g, qq.y, y1);
        y2 = fmaf(g, qq.z, y2);
      }
    }
  }

  const float cfe = -(y0 * y0 + y1 * y1 + y2 * y2) * inv2s2n;
  out[3 * n] = y0;
  out[3 * n + 1] = y1;
  out[3 * n + 2] = y2;

  float r = waveSum(cfe);
  if ((t & 63) == 0) s_red[t >> 6] = r;
  __syncthreads();
  if (t == 0) {
    float v = 0.f;
#pragma unroll
    for (int i = 0; i < 8; ++i) v += s_red[i];
    atomicAdd(&out[NPTS * 3], v);
  }
}

// ---------------------------------------------------------------------------
// Final (dense, round-0 structure, base-2): fallback if ws too small.
// ---------------------------------------------------------------------------
__global__ __launch_bounds__(512, 8) void k_final_dense(
    const float* __restrict__ X, const float4* __restrict__ pm,
    const float4* __restrict__ pq, const float* __restrict__ misc,
    float* __restrict__ out) {
  __shared__ float4 s_y[4][128];
  __shared__ float  s_red[8];

  const int t = threadIdx.x;
  const int p = t & 127;
  const int ch = __builtin_amdgcn_readfirstlane(t >> 7);
  const int n = blockIdx.x * 128 + p;
  const float x0 = X[3 * n], x1 = X[3 * n + 1], x2 = X[3 * n + 2];
  const float z = out[3 * n];
  const float inv2s2n = misc[1];

  const float4* __restrict__ pmc = pm + ch * 128;
  const float4* __restrict__ pqc = pq + ch * 128;
  float y0 = 0.f, y1 = 0.f, y2 = 0.f;
#pragma unroll 4
  for (int i = 0; i < 128; ++i) {
    float4 pp = pmc[i];
    float4 qq = pqc[i];
    const float l = fmaf(pp.x, x0, fmaf(pp.y, x1, fmaf(pp.z, x2, pp.w))) - z;
    const float g = exp2f(l);
    y0 = fmaf(g, qq.x, y0);
    y1 = fmaf(g, qq.y, y1);
    y2 = fmaf(g, qq.z, y2);
  }
  s_y[ch][p] = make_float4(y0, y1, y2, 0.f);
  __syncthreads();

  float cfe = 0.f;
  if (t < 128) {
    float4 a0 = s_y[0][t], a1 = s_y[1][t], a2 = s_y[2][t], a3 = s_y[3][t];
    const float Y0 = (a0.x + a1.x) + (a2.x + a3.x);
    const float Y1 = (a0.y + a1.y) + (a2.y + a3.y);
    const float Y2 = (a0.z + a1.z) + (a2.z + a3.z);
    cfe = -(Y0 * Y0 + Y1 * Y1 + Y2 * Y2) * inv2s2n;
    out[3 * n] = Y0;
    out[3 * n + 1] = Y1;
    out[3 * n + 2] = Y2;
  }
  float r = waveSum(cfe);
  if ((t & 63) == 0) s_red[t >> 6] = r;
  __syncthreads();
  if (t == 0) {
    float v = 0.f;
#pragma unroll
    for (int i = 0; i < 8; ++i) v += s_red[i];
    atomicAdd(&out[NPTS * 3], v);
  }
}

extern "C" void kernel_launch(void* const* d_in, const int* in_sizes, int n_in,
                              void* d_out, int out_size, void* d_ws, size_t ws_size,
                              hipStream_t stream) {
  const float* X = (const float*)d_in[0];
  const float* mu = (const float*)d_in[1];
  const float* w = (const float*)d_in[2];
  const float* sigma = (const float*)d_in[3];
  float* out = (float*)d_out;
  float* ws = (float*)d_ws;

  float4* pm = (float4*)(ws + PM4_OFF);
  float4* pq = (float4*)(ws + PQ4_OFF);
  float* ST = ws + ST4_OFF;
  float* misc = ws + MISC_OFF;

  const size_t need = (size_t)PL_OFF * 4 + (size_t)NPTS * 32;  // ~4.26 MB
  unsigned short* plist =
      (ws_size >= need) ? (unsigned short*)(ws + PL_OFF) : (unsigned short*)0;

  k_prep<<<1, 512, 0, stream>>>(mu, w, sigma, pm, ST, misc);
  k_estep<<<NPTS / 128, 512, 0, stream>>>(X, pm, ST, misc, out, plist);
  k_mstep<<<1, 512, 0, stream>>>(mu, (const float4*)ST, pq, misc, out);
  if (plist)
    k_final_list<<<NPTS / 512, 512, 0, stream>>>(X, pm, pq, misc, out, plist);
  else
    k_final_dense<<<NPTS / 128, 512, 0, stream>>>(X, pm, pq, misc, out);
}

// Round 3
// 158.845 us; speedup vs baseline: 1.1033x; 1.0152x over previous
//
#include <hip/hip_runtime.h>
#include <cfloat>
#include <cmath>

#define NPTS 131072
#define NC   512
#define NREP 4
#define L2E  1.4426950408889634f
#define LN2  0.6931471805599453f
// log2-domain relevance cutoff: gamma < 2^-34 contributes < 6e-11 per pair.
// Validated: rounds 0/1/2 all have identical absmax with/without this cut.
#define CUT  34.0f
#define ECAP 2048   // block-level entry capacity (mean ~333; >19 sigma margin)
#define PK   15     // per-point id slots (overflow -> dense fallback in final)

// ws float-index layout:
//  PM4  [0, 2048)      : per-component float4, BASE-2 scaled
//  PQ4  [2048, 4096)   : per-component float4 (mu_new[3], A_c)
//  ST4  [4096, 12288)  : NREP replicas x 512 comps x float4 (Tx,Ty,Tz,S)
//  MISC [12288, 12296) : [0]=sum|x|^2, [1]=inv2s2_new, [3]=sum(gamma*lgamma)
//  PL   [16384, ...)   : per-point u16[16]: [cnt|0xFFFF, id0..id14]  (4 MB)
// z_n (base-2 units) staged in d_out[3n] (k_estep writes, k_final reads then overwrites).
#define PM4_OFF  0
#define PQ4_OFF  2048
#define ST4_OFF  4096
#define MISC_OFF 12288
#define PL_OFF   16384

__device__ __forceinline__ float waveSum(float v) {
#pragma unroll
  for (int off = 32; off > 0; off >>= 1) v += __shfl_down(v, off, 64);
  return v;
}
__device__ __forceinline__ float waveMax(float v) {
#pragma unroll
  for (int off = 32; off > 0; off >>= 1) v = fmaxf(v, __shfl_down(v, off, 64));
  return v;
}
__device__ __forceinline__ unsigned lanePrefix(unsigned long long m) {
  return __builtin_amdgcn_mbcnt_hi(
      (unsigned)(m >> 32), __builtin_amdgcn_mbcnt_lo((unsigned)m, 0u));
}

// ---------------------------------------------------------------------------
// Prep: fold sigma/mu/w into packed pm, base-2 scaled (each exp = v_exp_f32).
// ---------------------------------------------------------------------------
__global__ __launch_bounds__(512) void k_prep(
    const float* __restrict__ mu, const float* __restrict__ w,
    const float* __restrict__ sigma, float4* __restrict__ pm,
    float* __restrict__ ST, float* __restrict__ misc) {
  const int t = threadIdx.x;  // component id
  const float sg = sigma[0];
  const float k2 = L2E / (2.0f * sg * sg);  // log2e * inv2s2
  const float m0 = mu[3 * t], m1 = mu[3 * t + 1], m2 = mu[3 * t + 2];
  pm[t] = make_float4(2.0f * k2 * m0, 2.0f * k2 * m1, 2.0f * k2 * m2,
                      w[t] * L2E - (m0 * m0 + m1 * m1 + m2 * m2) * k2);
#pragma unroll
  for (int r = 0; r < NREP * 4; ++r) ST[r * 512 + t] = 0.f;
  if (t < 8) misc[t] = 0.f;
}

// ---------------------------------------------------------------------------
// E-step: block = 512 thr = 128 points x 4 comp-chunks (128 comps each).
// Pass 1 (dense): l + per-chunk max (round-0 codegen: no side effects).
// Pass 2 (dense recompute, wave-uniform gated tail): no-hit path has zero
//   memory side effects; hit path (P~0.27/wave-iter) does ballot-compacted
//   push with ONE lane-0 LDS atomic + per-lane LDS stores at distinct slots.
// Pass 3: ~333 entries -> 4 global ST atomics + plist id write each.
// ---------------------------------------------------------------------------
__global__ __launch_bounds__(512, 4) void k_estep(
    const float* __restrict__ X, const float4* __restrict__ pm,
    float* __restrict__ ST, float* __restrict__ misc,
    float* __restrict__ out, unsigned short* __restrict__ plist) {
  __shared__ float4 s_pt[128];      // x0,x1,x2, (.w = z after combine)
  __shared__ float  s_m[4][128];    // per-(chunk,point) max
  __shared__ float2 s_sq[4][128];   // per-(chunk,point) (sumexp, q)
  __shared__ float  s_M[128];       // per-point global max
  __shared__ unsigned int s_cnt;    // block entry count
  __shared__ unsigned int s_pcnt[128];
  __shared__ unsigned int s_ec[ECAP];  // packed (p<<16)|c
  __shared__ float        s_el[ECAP];  // l for that entry

  const int t = threadIdx.x;
  const int p = t & 127;
  const int ch = __builtin_amdgcn_readfirstlane(t >> 7);  // wave-uniform
  const int n = blockIdx.x * 128 + p;
  const float x0 = X[3 * n], x1 = X[3 * n + 1], x2 = X[3 * n + 2];

  if (t == 0) s_cnt = 0u;
  if (t < 128) {
    s_pcnt[t] = 0u;
    s_pt[t] = make_float4(x0, x1, x2, 0.f);  // p == t here
  }

  // --- pass 1: dense l + chunk max (no storage, no side effects) ---
  const float4* __restrict__ pmc = pm + ch * 128;  // wave-uniform
  float ma = -FLT_MAX, mb = -FLT_MAX, mc2 = -FLT_MAX, md = -FLT_MAX;
#pragma unroll 4
  for (int i = 0; i < 128; i += 4) {
    float4 a = pmc[i], b = pmc[i + 1], c = pmc[i + 2], d = pmc[i + 3];
    ma  = fmaxf(ma,  fmaf(a.x, x0, fmaf(a.y, x1, fmaf(a.z, x2, a.w))));
    mb  = fmaxf(mb,  fmaf(b.x, x0, fmaf(b.y, x1, fmaf(b.z, x2, b.w))));
    mc2 = fmaxf(mc2, fmaf(c.x, x0, fmaf(c.y, x1, fmaf(c.z, x2, c.w))));
    md  = fmaxf(md,  fmaf(d.x, x0, fmaf(d.y, x1, fmaf(d.z, x2, d.w))));
  }
  s_m[ch][p] = fmaxf(fmaxf(ma, mb), fmaxf(mc2, md));
  __syncthreads();  // B1 (also publishes init writes)

  if (t < 128) {
    s_M[t] = fmaxf(fmaxf(s_m[0][t], s_m[1][t]), fmaxf(s_m[2][t], s_m[3][t]));
  }
  __syncthreads();  // B2

  const float M = s_M[p];
  const float thr = M - CUT;
  const int cbase = ch * 128;

  // --- pass 2: dense recompute; wave-uniform hit handling ---
  float sE = 0.f, qE = 0.f;
#pragma unroll 2
  for (int i = 0; i < 128; ++i) {
    float4 a = pmc[i];
    const float l = fmaf(a.x, x0, fmaf(a.y, x1, fmaf(a.z, x2, a.w)));
    const bool hit = (l >= thr);
    const unsigned long long mask = __ballot(hit);
    if (mask) {  // wave-uniform branch, ~27% of iterations
      const float d = l - M;
      const float e = exp2f(d);  // non-hit lanes underflow to ~0: harmless
      sE += e;
      qE = fmaf(e, d, qE);
      unsigned base;
      if ((t & 63) == 0) base = atomicAdd(&s_cnt, (unsigned)__popcll(mask));
      base = __builtin_amdgcn_readfirstlane(base);
      if (hit) {
        const unsigned idx = base + lanePrefix(mask);
        if (idx < (unsigned)ECAP) {
          s_ec[idx] = ((unsigned)p << 16) | (unsigned)(cbase + i);
          s_el[idx] = l;
        }
      }
    }
  }
  s_sq[ch][p] = make_float2(sE, qE);
  __syncthreads();  // B3

  if (t < 128) {  // p == t: combine chunks; emit z, La, reductions
    float2 q0 = s_sq[0][t], q1 = s_sq[1][t], q2 = s_sq[2][t], q3 = s_sq[3][t];
    const float ss = (q0.x + q1.x) + (q2.x + q3.x);  // >= 1 (max term present)
    const float qq = (q0.y + q1.y) + (q2.y + q3.y);
    const float lg = __log2f(ss);
    const float z = s_M[t] + lg;
    s_pt[t].w = z;
    out[3 * n] = z;  // staged for k_final (base-2)
    const float La = LN2 * (__fdividef(qq, ss) - lg);  // sum_c gamma*lgamma
    const float xx = x0 * x0 + x1 * x1 + x2 * x2;
    const float rl = waveSum(La);
    const float rx = waveSum(xx);
    if ((t & 63) == 0) { atomicAdd(&misc[3], rl); atomicAdd(&misc[0], rx); }
  }
  __syncthreads();  // B4: s_ec/s_el/s_cnt/s_pt.w all visible

  // --- pass 3: entries -> global ST atomics + plist ids ---
  const unsigned total = min(s_cnt, (unsigned)ECAP);
  float* __restrict__ stbase = ST + ((blockIdx.x & (NREP - 1)) * 512) * 4;
  const int bn = blockIdx.x * 128;
  for (unsigned idx = t; idx < total; idx += 512) {
    const unsigned ec = s_ec[idx];
    const unsigned pp = ec >> 16;
    const unsigned c = ec & 0xFFFFu;
    const float4 pt = s_pt[pp];
    const float g = exp2f(s_el[idx] - pt.w);
    float* st = stbase + c * 4;
    atomicAdd(st + 0, g * pt.x);
    atomicAdd(st + 1, g * pt.y);
    atomicAdd(st + 2, g * pt.z);
    atomicAdd(st + 3, g);
    if (plist) {
      const unsigned slot = atomicAdd(&s_pcnt[pp], 1u);
      if (slot < (unsigned)PK)
        plist[(size_t)(bn + pp) * 16u + 1u + slot] = (unsigned short)c;
    }
  }
  __syncthreads();  // B5: s_pcnt final
  if (plist && t < 128) {
    const unsigned pc = s_pcnt[t];
    plist[(size_t)(bn + t) * 16u] =
        (pc > (unsigned)PK) ? (unsigned short)0xFFFFu : (unsigned short)pc;
  }
}

// ---------------------------------------------------------------------------
// M-step: one block, 512 threads (one per component). Unchanged math.
// ---------------------------------------------------------------------------
__global__ __launch_bounds__(512) void k_mstep(
    const float* __restrict__ mu, const float4* __restrict__ ST4,
    float4* __restrict__ pq, float* __restrict__ misc,
    float* __restrict__ out) {
  __shared__ float s_red[8];
  __shared__ float s_red2[8];
  __shared__ float s_bc[4];
  const int t = threadIdx.x;

  float Tx = 0.f, Ty = 0.f, Tz = 0.f, S = 0.f;
#pragma unroll
  for (int r = 0; r < NREP; ++r) {
    float4 v = ST4[r * 512 + t];
    Tx += v.x; Ty += v.y; Tz += v.z; S += v.w;
  }
  const float Sc = fmaxf(S, 1e-30f);
  const float h = __logf(Sc);
  const float m0 = Tx / Sc, m1 = Ty / Sc, m2 = Tz / Sc;

  const float o0 = mu[3 * t], o1 = mu[3 * t + 1], o2 = mu[3 * t + 2];
  const float gdp = S * (o0 * o0 + o1 * o1 + o2 * o2)
                    - 2.0f * (o0 * Tx + o1 * Ty + o2 * Tz);

  float hm = waveMax(h);
  if ((t & 63) == 0) s_red[t >> 6] = hm;
  __syncthreads();
  if (t == 0) {
    float v = s_red[0];
    for (int i = 1; i < 8; ++i) v = fmaxf(v, s_red[i]);
    s_bc[0] = v;
  }
  __syncthreads();
  const float hM = s_bc[0];

  float es = waveSum(__expf(h - hM));
  float gs = waveSum(gdp);
  if ((t & 63) == 0) { s_red[t >> 6] = es; s_red2[t >> 6] = gs; }
  __syncthreads();
  if (t == 0) {
    float esum = 0.f, gsum = 0.f;
    for (int i = 0; i < 8; ++i) { esum += s_red[i]; gsum += s_red2[i]; }
    s_bc[1] = hM + __logf(esum);                           // lse(h)
    const float gd = fmaxf(misc[0] + gsum, 1e-20f);
    const float sn2 = gd * (1.0f / (3.0f * (float)NPTS));  // sigma_new^2
    s_bc[2] = 1.0f / (2.0f * sn2);                         // inv2s2_new
    s_bc[3] = 1.5f * __logf(sn2);                          // d*log(sigma_new)
  }
  __syncthreads();

  const float inv2s2n = s_bc[2];
  const float logpi = h - s_bc[1];
  const float A = (m0 * m0 + m1 * m1 + m2 * m2) * inv2s2n - logpi;
  pq[t] = make_float4(m0, m1, m2, A);

  float ca = waveSum(S * A);
  if ((t & 63) == 0) s_red[t >> 6] = ca;
  __syncthreads();
  if (t == 0) {
    float v = 0.f;
    for (int i = 0; i < 8; ++i) v += s_red[i];
    out[NPTS * 3] = v + misc[3] + (float)NPTS * s_bc[3];
    misc[1] = inv2s2n;
  }
}

// ---------------------------------------------------------------------------
// Final (list): thread-per-point, 512/block. Reads the per-point id list
// (avg ~2.6 comps); pm/pq LDS-staged. cnt=0xFFFF -> per-lane dense fallback.
// ---------------------------------------------------------------------------
__global__ __launch_bounds__(512, 4) void k_final_list(
    const float* __restrict__ X, const float4* __restrict__ pm,
    const float4* __restrict__ pq, const float* __restrict__ misc,
    float* __restrict__ out, const unsigned short* __restrict__ plist) {
  __shared__ float4 s_pm[NC];
  __shared__ float4 s_pq[NC];
  __shared__ float  s_red[8];

  const int t = threadIdx.x;
  const int n = blockIdx.x * 512 + t;

  s_pm[t] = pm[t];
  s_pq[t] = pq[t];

  const float x0 = X[3 * n], x1 = X[3 * n + 1], x2 = X[3 * n + 2];
  const float z = out[3 * n];  // staged by k_estep (base-2)
  const float inv2s2n = misc[1];

  const uint4* __restrict__ lp =
      reinterpret_cast<const uint4*>(plist) + ((size_t)n << 1);
  const uint4 wA = lp[0];
  const uint4 wB = lp[1];
  unsigned int words[8] = {wA.x, wA.y, wA.z, wA.w, wB.x, wB.y, wB.z, wB.w};
  const unsigned int cnt = words[0] & 0xFFFFu;
  __syncthreads();

  float y0 = 0.f, y1 = 0.f, y2 = 0.f;
  if (cnt == 0xFFFFu) {
    // dense fallback for overflowed points (astronomically rare)
    const float thr = z - CUT;
    for (int c = 0; c < NC; ++c) {
      float4 pp = s_pm[c];
      const float l = fmaf(pp.x, x0, fmaf(pp.y, x1, fmaf(pp.z, x2, pp.w)));
      if (l >= thr) {
        const float g = exp2f(l - z);
        float4 qq = s_pq[c];
        y0 = fmaf(g, qq.x, y0);
        y1 = fmaf(g, qq.y, y1);
        y2 = fmaf(g, qq.z, y2);
      }
    }
  } else {
    const int ic = (int)cnt;
#pragma unroll
    for (int j = 0; j < PK; ++j) {
      if (!__any(j < ic)) break;  // wave-uniform early exit (max cnt ~6)
      if (j < ic) {
        const unsigned int word = words[(j + 1) >> 1];
        const unsigned int c =
            ((j + 1) & 1) ? (word >> 16) : (word & 0xFFFFu);
        float4 pp = s_pm[c];
        const float l = fmaf(pp.x, x0, fmaf(pp.y, x1, fmaf(pp.z, x2, pp.w)));
        const float g = exp2f(l - z);
        float4 qq = s_pq[c];
        y0 = fmaf(g, qq.x, y0);
        y1 = fmaf(g, qq.y, y1);
        y2 = fmaf(g, qq.z, y2);
      }
    }
  }

  const float cfe = -(y0 * y0 + y1 * y1 + y2 * y2) * inv2s2n;
  out[3 * n] = y0;
  out[3 * n + 1] = y1;
  out[3 * n + 2] = y2;

  float r = waveSum(cfe);
  if ((t & 63) == 0) s_red[t >> 6] = r;
  __syncthreads();
  if (t == 0) {
    float v = 0.f;
#pragma unroll
    for (int i = 0; i < 8; ++i) v += s_red[i];
    atomicAdd(&out[NPTS * 3], v);
  }
}

// ---------------------------------------------------------------------------
// Final (dense, round-0 structure, base-2): fallback if ws too small.
// ---------------------------------------------------------------------------
__global__ __launch_bounds__(512, 8) void k_final_dense(
    const float* __restrict__ X, const float4* __restrict__ pm,
    const float4* __restrict__ pq, const float* __restrict__ misc,
    float* __restrict__ out) {
  __shared__ float4 s_y[4][128];
  __shared__ float  s_red[8];

  const int t = threadIdx.x;
  const int p = t & 127;
  const int ch = __builtin_amdgcn_readfirstlane(t >> 7);
  const int n = blockIdx.x * 128 + p;
  const float x0 = X[3 * n], x1 = X[3 * n + 1], x2 = X[3 * n + 2];
  const float z = out[3 * n];
  const float inv2s2n = misc[1];

  const float4* __restrict__ pmc = pm + ch * 128;
  const float4* __restrict__ pqc = pq + ch * 128;
  float y0 = 0.f, y1 = 0.f, y2 = 0.f;
#pragma unroll 4
  for (int i = 0; i < 128; ++i) {
    float4 pp = pmc[i];
    float4 qq = pqc[i];
    const float l = fmaf(pp.x, x0, fmaf(pp.y, x1, fmaf(pp.z, x2, pp.w))) - z;
    const float g = exp2f(l);
    y0 = fmaf(g, qq.x, y0);
    y1 = fmaf(g, qq.y, y1);
    y2 = fmaf(g, qq.z, y2);
  }
  s_y[ch][p] = make_float4(y0, y1, y2, 0.f);
  __syncthreads();

  float cfe = 0.f;
  if (t < 128) {
    float4 a0 = s_y[0][t], a1 = s_y[1][t], a2 = s_y[2][t], a3 = s_y[3][t];
    const float Y0 = (a0.x + a1.x) + (a2.x + a3.x);
    const float Y1 = (a0.y + a1.y) + (a2.y + a3.y);
    const float Y2 = (a0.z + a1.z) + (a2.z + a3.z);
    cfe = -(Y0 * Y0 + Y1 * Y1 + Y2 * Y2) * inv2s2n;
    out[3 * n] = Y0;
    out[3 * n + 1] = Y1;
    out[3 * n + 2] = Y2;
  }
  float r = waveSum(cfe);
  if ((t & 63) == 0) s_red[t >> 6] = r;
  __syncthreads();
  if (t == 0) {
    float v = 0.f;
#pragma unroll
    for (int i = 0; i < 8; ++i) v += s_red[i];
    atomicAdd(&out[NPTS * 3], v);
  }
}

extern "C" void kernel_launch(void* const* d_in, const int* in_sizes, int n_in,
                              void* d_out, int out_size, void* d_ws, size_t ws_size,
                              hipStream_t stream) {
  const float* X = (const float*)d_in[0];
  const float* mu = (const float*)d_in[1];
  const float* w = (const float*)d_in[2];
  const float* sigma = (const float*)d_in[3];
  float* out = (float*)d_out;
  float* ws = (float*)d_ws;

  float4* pm = (float4*)(ws + PM4_OFF);
  float4* pq = (float4*)(ws + PQ4_OFF);
  float* ST = ws + ST4_OFF;
  float* misc = ws + MISC_OFF;

  const size_t need = (size_t)PL_OFF * 4 + (size_t)NPTS * 32;  // ~4.26 MB
  unsigned short* plist =
      (ws_size >= need) ? (unsigned short*)(ws + PL_OFF) : (unsigned short*)0;

  k_prep<<<1, 512, 0, stream>>>(mu, w, sigma, pm, ST, misc);
  k_estep<<<NPTS / 128, 512, 0, stream>>>(X, pm, ST, misc, out, plist);
  k_mstep<<<1, 512, 0, stream>>>(mu, (const float4*)ST, pq, misc, out);
  if (plist)
    k_final_list<<<NPTS / 512, 512, 0, stream>>>(X, pm, pq, misc, out, plist);
  else
    k_final_dense<<<NPTS / 128, 512, 0, stream>>>(X, pm, pq, misc, out);
}